// Round 4
// baseline (320.221 us; speedup 1.0000x reference)
//
#include <hip/hip_runtime.h>

#define LOG2E 1.44269504088896340736f

__device__ __forceinline__ float vexp2(float x){ float r; asm("v_exp_f32 %0, %1" : "=v"(r) : "v"(x)); return r; }
__device__ __forceinline__ float vrcp (float x){ float r; asm("v_rcp_f32 %0, %1" : "=v"(r) : "v"(x)); return r; }
__device__ __forceinline__ float rl(float v, int l){
  return __int_as_float(__builtin_amdgcn_readlane(__float_as_int(v), l));
}
template<int XM> __device__ __forceinline__ float swx(float v){
  return __int_as_float(__builtin_amdgcn_ds_swizzle(__float_as_int(v), (XM<<10)|0x1F));
}
__device__ __forceinline__ float sigm(float x){ return vrcp(1.0f + vexp2(x * (-LOG2E))); }
__device__ __forceinline__ float tanh_f(float x){
  float s = vrcp(1.0f + vexp2(x * (-2.0f*LOG2E)));
  return s + s - 1.0f;
}
// Pin a value into a register: inline-asm defs cannot be rematerialized.
// With waves_per_eu(4,4) the allocator has a 128-VGPR budget, so pinned
// weights stay in arch VGPRs instead of being reloaded every iteration.
#define PIN(v) asm volatile("" : "+v"(v))

__global__ void __launch_bounds__(64)
__attribute__((amdgpu_waves_per_eu(4, 4)))
lstm_ae_fused(const float* __restrict__ x,
              const float* __restrict__ e1Wi, const float* __restrict__ e1Wh, const float* __restrict__ e1bi, const float* __restrict__ e1bh,
              const float* __restrict__ e2Wi, const float* __restrict__ e2Wh, const float* __restrict__ e2bi, const float* __restrict__ e2bh,
              const float* __restrict__ e3Wi, const float* __restrict__ e3Wh, const float* __restrict__ e3bi, const float* __restrict__ e3bh,
              const float* __restrict__ d1Wi, const float* __restrict__ d1Wh, const float* __restrict__ d1bi, const float* __restrict__ d1bh,
              const float* __restrict__ d2Wi, const float* __restrict__ d2Wh, const float* __restrict__ d2bi, const float* __restrict__ d2bh,
              const float* __restrict__ d3Wi, const float* __restrict__ d3Wh, const float* __restrict__ d3bi, const float* __restrict__ d3bh,
              const float* __restrict__ Wout, const float* __restrict__ bout,
              float* __restrict__ out)
{
  const int lane = threadIdx.x;          // 0..63, one wave per block
  const int b    = blockIdx.x;           // one batch element per wave
  const float* __restrict__ xb = x   + (size_t)b * (128*32);
  float*       __restrict__ ob = out + (size_t)b * (128*32);

  // gate-role masks (PyTorch order i,f,g,o): g-chunk lanes get tanh
  const bool isg1 = (lane >= 32) && (lane < 48);              // e1/d3 h=16
  const bool isg2 = ((lane & 15) >= 8) && ((lane & 15) < 12); // e2/d1 h=4
  const bool isg3 = ((lane & 3) == 2);                        // e3 h=1
  const bool isgD2= ((lane & 31) >= 16) && ((lane & 31) < 24);// d2 h=8

  const float A1 = isg1 ? 2.f : 1.f,  B1 = isg1 ? -1.f : 0.f;
  const float A2 = isg2 ? 2.f : 1.f,  B2 = isg2 ? -1.f : 0.f;
  const float A3 = isg3 ? 2.f : 1.f,  B3 = isg3 ? -1.f : 0.f;
  const float AD2= isgD2? 2.f : 1.f,  BD2= isgD2? -1.f : 0.f;

  float enc;
  // ======================= ENCODER =======================
  {
    // weights (g-gate rows pre-scaled x2 so tanh(x) = 2*sigm(2x)-1 needs no extra mul)
    float w1i[32], w1h[16], eb1;
    {
      const int g = lane;
      #pragma unroll
      for (int k=0;k<32;++k){ w1i[k] = e1Wi[g*32+k]*A1; PIN(w1i[k]); }
      #pragma unroll
      for (int k=0;k<16;++k){ w1h[k] = e1Wh[g*16+k]*A1; PIN(w1h[k]); }
      eb1 = (e1bi[g] + e1bh[g])*A1; PIN(eb1);
    }
    float w2i[16], w2h[4], eb2;
    {
      const int g = lane & 15;
      #pragma unroll
      for (int k=0;k<16;++k){ w2i[k] = e2Wi[g*16+k]*A2; PIN(w2i[k]); }
      #pragma unroll
      for (int k=0;k<4;++k){ w2h[k] = e2Wh[g*4+k]*A2; PIN(w2h[k]); }
      eb2 = (e2bi[g] + e2bh[g])*A2; PIN(eb2);
    }
    float w3i[4], w3h, eb3;
    {
      const int g = lane & 3;
      #pragma unroll
      for (int k=0;k<4;++k){ w3i[k] = e3Wi[g*4+k]*A3; PIN(w3i[k]); }
      w3h = e3Wh[g]*A3; PIN(w3h);
      eb3 = (e3bi[g] + e3bh[g])*A3; PIN(eb3);
    }

    float h1s[16], h2s[4], h3s = 0.f, c1 = 0.f, c2 = 0.f, c3 = 0.f;
    #pragma unroll
    for (int k=0;k<16;++k) h1s[k] = 0.f;
    #pragma unroll
    for (int k=0;k<4;++k)  h2s[k] = 0.f;

    #pragma unroll 1
    for (int t=0;t<128;++t){
      const float* __restrict__ xt = xb + t*32;     // wave-uniform -> scalar loads
      float xv[32];
      #pragma unroll
      for (int k=0;k<32;++k) xv[k] = xt[k];

      // ---- e1: din=32, h=16 (gate-per-lane, 64 gates)
      float a0=eb1, a1=0.f, a2=0.f, a3=0.f;
      #pragma unroll
      for (int k=0;k<32;k+=4){
        a0 = fmaf(w1i[k  ], xv[k  ], a0);
        a1 = fmaf(w1i[k+1], xv[k+1], a1);
        a2 = fmaf(w1i[k+2], xv[k+2], a2);
        a3 = fmaf(w1i[k+3], xv[k+3], a3);
      }
      #pragma unroll
      for (int k=0;k<16;k+=4){
        a0 = fmaf(w1h[k  ], h1s[k  ], a0);
        a1 = fmaf(w1h[k+1], h1s[k+1], a1);
        a2 = fmaf(w1h[k+2], h1s[k+2], a2);
        a3 = fmaf(w1h[k+3], h1s[k+3], a3);
      }
      float v = fmaf(sigm((a0+a1)+(a2+a3)), A1, B1);
      float f = swx<16>(v);
      float g = __shfl_xor(v, 32, 64);
      float o = __shfl_xor(f, 32, 64);
      c1 = fmaf(f, c1, v*g);                        // valid lanes 0..15
      float h1 = o * tanh_f(c1);
      #pragma unroll
      for (int k=0;k<16;++k) h1s[k] = rl(h1, k);    // -> SGPRs

      // ---- e2: din=16, h=4
      a0 = eb2; a1 = 0.f;
      #pragma unroll
      for (int k=0;k<16;k+=2){ a0 = fmaf(w2i[k], h1s[k], a0); a1 = fmaf(w2i[k+1], h1s[k+1], a1); }
      #pragma unroll
      for (int k=0;k<4;k+=2){ a0 = fmaf(w2h[k], h2s[k], a0); a1 = fmaf(w2h[k+1], h2s[k+1], a1); }
      v = fmaf(sigm(a0+a1), A2, B2);
      f = swx<4>(v);  g = swx<8>(v);  o = swx<12>(v);
      c2 = fmaf(f, c2, v*g);                        // valid lanes 0..3
      float h2 = o * tanh_f(c2);
      #pragma unroll
      for (int k=0;k<4;++k) h2s[k] = rl(h2, k);

      // ---- e3: din=4, h=1
      float a = eb3;
      #pragma unroll
      for (int k=0;k<4;++k) a = fmaf(w3i[k], h2s[k], a);
      a = fmaf(w3h, h3s, a);
      v = fmaf(sigm(a), A3, B3);
      f = swx<1>(v);  g = swx<2>(v);  o = swx<3>(v);
      c3 = fmaf(f, c3, v*g);                        // valid lane 0
      h3s = rl(o * tanh_f(c3), 0);
    }
    enc = h3s;
  }

  // ======================= DECODER =======================
  {
    float p1, wd1h[4];
    {
      const int g = lane & 15;                       // d1: din=1, h=4
      float wi = d1Wi[g]*A2;
      #pragma unroll
      for (int k=0;k<4;++k){ wd1h[k] = d1Wh[g*4+k]*A2; PIN(wd1h[k]); }
      p1 = fmaf(wi, enc, (d1bi[g] + d1bh[g])*A2);    // constant over t
      PIN(p1);
    }
    float wd2i[4], wd2h[8], bd2;
    {
      const int g = lane & 31;                       // d2: din=4, h=8
      #pragma unroll
      for (int k=0;k<4;++k){ wd2i[k] = d2Wi[g*4+k]*AD2; PIN(wd2i[k]); }
      #pragma unroll
      for (int k=0;k<8;++k){ wd2h[k] = d2Wh[g*8+k]*AD2; PIN(wd2h[k]); }
      bd2 = (d2bi[g] + d2bh[g])*AD2; PIN(bd2);
    }
    float wd3i[8], wd3h[16], bd3;
    {
      const int g = lane;                            // d3: din=8, h=16
      #pragma unroll
      for (int k=0;k<8;++k){  wd3i[k] = d3Wi[g*8+k]*A1; PIN(wd3i[k]); }
      #pragma unroll
      for (int k=0;k<16;++k){ wd3h[k] = d3Wh[g*16+k]*A1; PIN(wd3h[k]); }
      bd3 = (d3bi[g] + d3bh[g])*A1; PIN(bd3);
    }
    float wo[16], bo;
    {
      const int g = lane & 31;                       // final linear: 32 outputs
      #pragma unroll
      for (int k=0;k<16;++k){ wo[k] = Wout[g*16+k]; PIN(wo[k]); }
      bo = bout[g]; PIN(bo);
    }

    float hd1[4], hd2[8], hd3[16];
    #pragma unroll
    for (int k=0;k<4;++k)  hd1[k] = 0.f;
    #pragma unroll
    for (int k=0;k<8;++k)  hd2[k] = 0.f;
    #pragma unroll
    for (int k=0;k<16;++k) hd3[k] = 0.f;
    float dc1 = 0.f, dc2 = 0.f, dc3 = 0.f;

    #pragma unroll 1
    for (int t=0;t<128;++t){
      // ---- d1: din=1 (constant input term), h=4
      float a0 = p1, a1 = 0.f;
      #pragma unroll
      for (int k=0;k<4;k+=2){ a0 = fmaf(wd1h[k], hd1[k], a0); a1 = fmaf(wd1h[k+1], hd1[k+1], a1); }
      float v = fmaf(sigm(a0+a1), A2, B2);
      float f = swx<4>(v);  float g = swx<8>(v);  float o = swx<12>(v);
      dc1 = fmaf(f, dc1, v*g);                      // valid lanes 0..3
      float h1 = o * tanh_f(dc1);
      #pragma unroll
      for (int k=0;k<4;++k) hd1[k] = rl(h1, k);

      // ---- d2: din=4, h=8
      a0 = bd2; a1 = 0.f;
      #pragma unroll
      for (int k=0;k<4;k+=2){ a0 = fmaf(wd2i[k], hd1[k], a0); a1 = fmaf(wd2i[k+1], hd1[k+1], a1); }
      #pragma unroll
      for (int k=0;k<8;k+=2){ a0 = fmaf(wd2h[k], hd2[k], a0); a1 = fmaf(wd2h[k+1], hd2[k+1], a1); }
      v = fmaf(sigm(a0+a1), AD2, BD2);
      f = swx<8>(v);  g = swx<16>(v);  o = swx<24>(v);
      dc2 = fmaf(f, dc2, v*g);                      // valid lanes 0..7
      float h2 = o * tanh_f(dc2);
      #pragma unroll
      for (int k=0;k<8;++k) hd2[k] = rl(h2, k);

      // ---- d3: din=8, h=16
      a0 = bd3; a1 = 0.f; float a2 = 0.f, a3 = 0.f;
      #pragma unroll
      for (int k=0;k<8;k+=4){
        a0 = fmaf(wd3i[k  ], hd2[k  ], a0);
        a1 = fmaf(wd3i[k+1], hd2[k+1], a1);
        a2 = fmaf(wd3i[k+2], hd2[k+2], a2);
        a3 = fmaf(wd3i[k+3], hd2[k+3], a3);
      }
      #pragma unroll
      for (int k=0;k<16;k+=4){
        a0 = fmaf(wd3h[k  ], hd3[k  ], a0);
        a1 = fmaf(wd3h[k+1], hd3[k+1], a1);
        a2 = fmaf(wd3h[k+2], hd3[k+2], a2);
        a3 = fmaf(wd3h[k+3], hd3[k+3], a3);
      }
      v = fmaf(sigm((a0+a1)+(a2+a3)), A1, B1);
      f = swx<16>(v);
      g = __shfl_xor(v, 32, 64);
      o = __shfl_xor(f, 32, 64);
      dc3 = fmaf(f, dc3, v*g);                      // valid lanes 0..15
      float h3 = o * tanh_f(dc3);
      #pragma unroll
      for (int k=0;k<16;++k) hd3[k] = rl(h3, k);

      // ---- final linear 16->32, coalesced store
      float ov0 = bo, ov1 = 0.f;
      #pragma unroll
      for (int k=0;k<16;k+=2){ ov0 = fmaf(wo[k], hd3[k], ov0); ov1 = fmaf(wo[k+1], hd3[k+1], ov1); }
      if (lane < 32) ob[t*32 + lane] = ov0 + ov1;
    }
  }
}

extern "C" void kernel_launch(void* const* d_in, const int* in_sizes, int n_in,
                              void* d_out, int out_size, void* d_ws, size_t ws_size,
                              hipStream_t stream) {
  (void)in_sizes; (void)n_in; (void)d_ws; (void)ws_size; (void)out_size;
  const float* x    = (const float*)d_in[0];
  const float* e1Wi = (const float*)d_in[1];
  const float* e1Wh = (const float*)d_in[2];
  const float* e1bi = (const float*)d_in[3];
  const float* e1bh = (const float*)d_in[4];
  const float* e2Wi = (const float*)d_in[5];
  const float* e2Wh = (const float*)d_in[6];
  const float* e2bi = (const float*)d_in[7];
  const float* e2bh = (const float*)d_in[8];
  const float* e3Wi = (const float*)d_in[9];
  const float* e3Wh = (const float*)d_in[10];
  const float* e3bi = (const float*)d_in[11];
  const float* e3bh = (const float*)d_in[12];
  const float* d1Wi = (const float*)d_in[13];
  const float* d1Wh = (const float*)d_in[14];
  const float* d1bi = (const float*)d_in[15];
  const float* d1bh = (const float*)d_in[16];
  const float* d2Wi = (const float*)d_in[17];
  const float* d2Wh = (const float*)d_in[18];
  const float* d2bi = (const float*)d_in[19];
  const float* d2bh = (const float*)d_in[20];
  const float* d3Wi = (const float*)d_in[21];
  const float* d3Wh = (const float*)d_in[22];
  const float* d3bi = (const float*)d_in[23];
  const float* d3bh = (const float*)d_in[24];
  const float* Wout = (const float*)d_in[25];
  const float* boutp= (const float*)d_in[26];
  float* out = (float*)d_out;

  lstm_ae_fused<<<4096, 64, 0, stream>>>(x,
      e1Wi, e1Wh, e1bi, e1bh,
      e2Wi, e2Wh, e2bi, e2bh,
      e3Wi, e3Wh, e3bi, e3bh,
      d1Wi, d1Wh, d1bi, d1bh,
      d2Wi, d2Wh, d2bi, d2bh,
      d3Wi, d3Wh, d3bi, d3bh,
      Wout, boutp, out);
}

// Round 5
// 283.009 us; speedup vs baseline: 1.1315x; 1.1315x over previous
//
#include <hip/hip_runtime.h>

#define LOG2E 1.44269504088896340736f

__device__ __forceinline__ float vexp2(float x){ float r; asm("v_exp_f32 %0, %1" : "=v"(r) : "v"(x)); return r; }
__device__ __forceinline__ float vrcp (float x){ float r; asm("v_rcp_f32 %0, %1" : "=v"(r) : "v"(x)); return r; }
__device__ __forceinline__ float rl(float v, int l){
  return __int_as_float(__builtin_amdgcn_readlane(__float_as_int(v), l));
}
template<int XM> __device__ __forceinline__ float swx(float v){
  return __int_as_float(__builtin_amdgcn_ds_swizzle(__float_as_int(v), (XM<<10)|0x1F));
}
__device__ __forceinline__ float sigm(float x){ return vrcp(1.0f + vexp2(x * (-LOG2E))); }
__device__ __forceinline__ float tanh_f(float x){
  float s = vrcp(1.0f + vexp2(x * (-2.0f*LOG2E)));
  return s + s - 1.0f;
}

// Weights live in LDS, shared by the block's 4 waves (4 batch elements).
// In-loop weight reads are ds_read_b128 with immediate offsets: no VALU
// address math, no global remat, latency on the LDS pipe (overlaps VALU).
__global__ void __launch_bounds__(256, 4)
lstm_ae_fused(const float* __restrict__ x,
              const float* __restrict__ e1Wi, const float* __restrict__ e1Wh, const float* __restrict__ e1bi, const float* __restrict__ e1bh,
              const float* __restrict__ e2Wi, const float* __restrict__ e2Wh, const float* __restrict__ e2bi, const float* __restrict__ e2bh,
              const float* __restrict__ e3Wi, const float* __restrict__ e3Wh, const float* __restrict__ e3bi, const float* __restrict__ e3bh,
              const float* __restrict__ d1Wi, const float* __restrict__ d1Wh, const float* __restrict__ d1bi, const float* __restrict__ d1bh,
              const float* __restrict__ d2Wi, const float* __restrict__ d2Wh, const float* __restrict__ d2bi, const float* __restrict__ d2bh,
              const float* __restrict__ d3Wi, const float* __restrict__ d3Wh, const float* __restrict__ d3bi, const float* __restrict__ d3bh,
              const float* __restrict__ Wout, const float* __restrict__ bout,
              float* __restrict__ out)
{
  const int tid  = threadIdx.x;
  const int lane = tid & 63;
  const int wv   = tid >> 6;                 // wave id 0..3
  const int b    = blockIdx.x*4 + wv;        // batch element per wave
  const float* __restrict__ xb = x   + (size_t)b * (128*32);
  float*       __restrict__ ob = out + (size_t)b * (128*32);

  // ---------------- LDS ----------------
  __shared__ float s_e1[13*64*4];   // per-lane: grp0-7 w1i, grp8-11 w1h, grp12.x eb1
  __shared__ float s_e2[16*20];     // row r: [0..15] w2i, [16..19] w2h
  __shared__ float s_eb2[16];
  __shared__ float s_e3[4*8];       // row r: [0..3] w3i, [4] w3h, [5] eb3
  __shared__ float s_d1[16*8];      // row r: [0..3] wd1h, [4] d1Wi, [5] bd1
  __shared__ float s_d2[32*20];     // row r: [0..3] wd2i, [4..11] wd2h, [12] bd2
  __shared__ float s_d3[7*64*4];    // per-lane: grp0-1 wd3i, grp2-5 wd3h, grp6.x bd3
  __shared__ float s_wo[32*20];     // row r: [0..15] Wout, [16] bout
  __shared__ float s_x[4*512];      // per-wave 16-step x chunk

  // ---------------- one-time weight staging (g-gate rows pre-scaled x2) ----------------
  if (tid < 64){
    const int l = tid;
    const float A1l = (l>=32 && l<48) ? 2.f : 1.f;
    for (int k=0;k<32;++k) s_e1[((k>>2)*64+l)*4+(k&3)]      = e1Wi[l*32+k]*A1l;
    for (int k=0;k<16;++k) s_e1[(((k>>2)+8)*64+l)*4+(k&3)]  = e1Wh[l*16+k]*A1l;
    s_e1[(12*64+l)*4] = (e1bi[l]+e1bh[l])*A1l;
    for (int k=0;k<8;++k)  s_d3[((k>>2)*64+l)*4+(k&3)]      = d3Wi[l*8+k]*A1l;
    for (int k=0;k<16;++k) s_d3[(((k>>2)+2)*64+l)*4+(k&3)]  = d3Wh[l*16+k]*A1l;
    s_d3[(6*64+l)*4] = (d3bi[l]+d3bh[l])*A1l;
    if (l < 16){
      const float A2l = (l>=8 && l<12) ? 2.f : 1.f;
      for (int k=0;k<16;++k) s_e2[l*20+k]    = e2Wi[l*16+k]*A2l;
      for (int k=0;k<4;++k)  s_e2[l*20+16+k] = e2Wh[l*4+k]*A2l;
      s_eb2[l] = (e2bi[l]+e2bh[l])*A2l;
      for (int k=0;k<4;++k)  s_d1[l*8+k] = d1Wh[l*4+k]*A2l;
      s_d1[l*8+4] = d1Wi[l]*A2l;
      s_d1[l*8+5] = (d1bi[l]+d1bh[l])*A2l;
    }
    if (l < 4){
      const float A3l = (l==2) ? 2.f : 1.f;
      for (int k=0;k<4;++k) s_e3[l*8+k] = e3Wi[l*4+k]*A3l;
      s_e3[l*8+4] = e3Wh[l]*A3l;
      s_e3[l*8+5] = (e3bi[l]+e3bh[l])*A3l;
    }
    if (l < 32){
      const float AD2l = (l>=16 && l<24) ? 2.f : 1.f;
      for (int k=0;k<4;++k) s_d2[l*20+k]   = d2Wi[l*4+k]*AD2l;
      for (int k=0;k<8;++k) s_d2[l*20+4+k] = d2Wh[l*8+k]*AD2l;
      s_d2[l*20+12] = (d2bi[l]+d2bh[l])*AD2l;
      for (int k=0;k<16;++k) s_wo[l*20+k] = Wout[l*16+k];
      s_wo[l*20+16] = bout[l];
    }
  }
  __syncthreads();

  // gate-role output affine (A folded into weights; B applied after sigm)
  const bool isg1 = (lane >= 32) && (lane < 48);
  const bool isg2 = ((lane & 15) >= 8) && ((lane & 15) < 12);
  const bool isg3 = ((lane & 3) == 2);
  const bool isgD2= ((lane & 31) >= 16) && ((lane & 31) < 24);
  const float A1 = isg1 ? 2.f : 1.f,  B1 = isg1 ? -1.f : 0.f;
  const float A2 = isg2 ? 2.f : 1.f,  B2 = isg2 ? -1.f : 0.f;
  const float A3 = isg3 ? 2.f : 1.f,  B3 = isg3 ? -1.f : 0.f;
  const float AD2= isgD2? 2.f : 1.f,  BD2= isgD2? -1.f : 0.f;

  const float4* e1v = (const float4*)s_e1;
  const float4* d3v = (const float4*)s_d3;
  const float* r2 = &s_e2[(lane&15)*20];
  const float* r3 = &s_e3[(lane&3)*8];
  const float* rd1= &s_d1[(lane&15)*8];
  const float* rd2= &s_d2[(lane&31)*20];
  const float* rw = &s_wo[(lane&31)*20];

  float enc;
  // ======================= ENCODER =======================
  {
    const float eb1 = s_e1[(12*64+lane)*4];
    const float eb2 = s_eb2[lane&15];
    const float w3h = r3[4], eb3 = r3[5];

    float h1s[16], h2s[4], h3s = 0.f, c1 = 0.f, c2 = 0.f, c3 = 0.f;
    #pragma unroll
    for (int k=0;k<16;++k) h1s[k] = 0.f;
    #pragma unroll
    for (int k=0;k<4;++k)  h2s[k] = 0.f;

    for (int tc=0; tc<128; tc+=16){
      // stage this wave's next 16 steps of x into LDS (wave-internal, no barrier)
      {
        const float4* xg = (const float4*)(xb + tc*32);
        float4* sx = (float4*)&s_x[wv*512];
        sx[lane*2]   = xg[lane*2];
        sx[lane*2+1] = xg[lane*2+1];
      }
      #pragma unroll 2
      for (int tt=0; tt<16; ++tt){
        const float4* xv4 = (const float4*)&s_x[wv*512 + tt*32];

        // ---- e1: din=32, h=16 (gate-per-lane, 64 gates)
        float a0=eb1, a1=0.f, a2=0.f, a3=0.f;
        #pragma unroll
        for (int grp=0; grp<8; ++grp){
          float4 wq = e1v[grp*64+lane];
          float4 xq = xv4[grp];
          a0 = fmaf(wq.x, xq.x, a0);
          a1 = fmaf(wq.y, xq.y, a1);
          a2 = fmaf(wq.z, xq.z, a2);
          a3 = fmaf(wq.w, xq.w, a3);
        }
        #pragma unroll
        for (int grp=0; grp<4; ++grp){
          float4 wq = e1v[(8+grp)*64+lane];
          a0 = fmaf(wq.x, h1s[grp*4  ], a0);
          a1 = fmaf(wq.y, h1s[grp*4+1], a1);
          a2 = fmaf(wq.z, h1s[grp*4+2], a2);
          a3 = fmaf(wq.w, h1s[grp*4+3], a3);
        }
        float v = fmaf(sigm((a0+a1)+(a2+a3)), A1, B1);
        float f = swx<16>(v);
        float g = __shfl_xor(v, 32, 64);
        float o = __shfl_xor(f, 32, 64);
        c1 = fmaf(f, c1, v*g);                        // valid lanes 0..15
        float h1 = o * tanh_f(c1);
        #pragma unroll
        for (int k=0;k<16;++k) h1s[k] = rl(h1, k);    // -> SGPRs

        // ---- e2: din=16, h=4
        float4 w20 = *(const float4*)(r2);
        float4 w21 = *(const float4*)(r2+4);
        float4 w22 = *(const float4*)(r2+8);
        float4 w23 = *(const float4*)(r2+12);
        float4 w24 = *(const float4*)(r2+16);
        a0 = eb2; a1 = 0.f;
        a0 = fmaf(w20.x,h1s[0],a0);  a1 = fmaf(w20.y,h1s[1],a1);
        a0 = fmaf(w20.z,h1s[2],a0);  a1 = fmaf(w20.w,h1s[3],a1);
        a0 = fmaf(w21.x,h1s[4],a0);  a1 = fmaf(w21.y,h1s[5],a1);
        a0 = fmaf(w21.z,h1s[6],a0);  a1 = fmaf(w21.w,h1s[7],a1);
        a0 = fmaf(w22.x,h1s[8],a0);  a1 = fmaf(w22.y,h1s[9],a1);
        a0 = fmaf(w22.z,h1s[10],a0); a1 = fmaf(w22.w,h1s[11],a1);
        a0 = fmaf(w23.x,h1s[12],a0); a1 = fmaf(w23.y,h1s[13],a1);
        a0 = fmaf(w23.z,h1s[14],a0); a1 = fmaf(w23.w,h1s[15],a1);
        a0 = fmaf(w24.x,h2s[0],a0);  a1 = fmaf(w24.y,h2s[1],a1);
        a0 = fmaf(w24.z,h2s[2],a0);  a1 = fmaf(w24.w,h2s[3],a1);
        v = fmaf(sigm(a0+a1), A2, B2);
        f = swx<4>(v);  g = swx<8>(v);  o = swx<12>(v);
        c2 = fmaf(f, c2, v*g);                        // valid lanes 0..3
        float h2 = o * tanh_f(c2);
        #pragma unroll
        for (int k=0;k<4;++k) h2s[k] = rl(h2, k);

        // ---- e3: din=4, h=1
        float4 w30 = *(const float4*)(r3);
        float a = eb3;
        a = fmaf(w30.x, h2s[0], a);
        a = fmaf(w30.y, h2s[1], a);
        a = fmaf(w30.z, h2s[2], a);
        a = fmaf(w30.w, h2s[3], a);
        a = fmaf(w3h, h3s, a);
        v = fmaf(sigm(a), A3, B3);
        f = swx<1>(v);  g = swx<2>(v);  o = swx<3>(v);
        c3 = fmaf(f, c3, v*g);                        // valid lane 0
        h3s = rl(o * tanh_f(c3), 0);
      }
    }
    enc = h3s;
  }

  // ======================= DECODER =======================
  {
    const float p1  = fmaf(rd1[4], enc, rd1[5]);       // d1 input term, const over t
    const float bd2 = rd2[12];
    const float bd3 = s_d3[(6*64+lane)*4];
    const float bo  = rw[16];

    float hd1[4], hd2[8], hd3[16];
    #pragma unroll
    for (int k=0;k<4;++k)  hd1[k] = 0.f;
    #pragma unroll
    for (int k=0;k<8;++k)  hd2[k] = 0.f;
    #pragma unroll
    for (int k=0;k<16;++k) hd3[k] = 0.f;
    float dc1 = 0.f, dc2 = 0.f, dc3 = 0.f;

    #pragma unroll 2
    for (int t=0;t<128;++t){
      // ---- d1: din=1 (constant input term), h=4
      float4 wd1 = *(const float4*)(rd1);
      float a0 = p1, a1 = 0.f;
      a0 = fmaf(wd1.x, hd1[0], a0); a1 = fmaf(wd1.y, hd1[1], a1);
      a0 = fmaf(wd1.z, hd1[2], a0); a1 = fmaf(wd1.w, hd1[3], a1);
      float v = fmaf(sigm(a0+a1), A2, B2);
      float f = swx<4>(v);  float g = swx<8>(v);  float o = swx<12>(v);
      dc1 = fmaf(f, dc1, v*g);                      // valid lanes 0..3
      float h1 = o * tanh_f(dc1);
      #pragma unroll
      for (int k=0;k<4;++k) hd1[k] = rl(h1, k);

      // ---- d2: din=4, h=8
      float4 w2a = *(const float4*)(rd2);
      float4 w2b = *(const float4*)(rd2+4);
      float4 w2c = *(const float4*)(rd2+8);
      a0 = bd2; a1 = 0.f;
      a0 = fmaf(w2a.x, hd1[0], a0); a1 = fmaf(w2a.y, hd1[1], a1);
      a0 = fmaf(w2a.z, hd1[2], a0); a1 = fmaf(w2a.w, hd1[3], a1);
      a0 = fmaf(w2b.x, hd2[0], a0); a1 = fmaf(w2b.y, hd2[1], a1);
      a0 = fmaf(w2b.z, hd2[2], a0); a1 = fmaf(w2b.w, hd2[3], a1);
      a0 = fmaf(w2c.x, hd2[4], a0); a1 = fmaf(w2c.y, hd2[5], a1);
      a0 = fmaf(w2c.z, hd2[6], a0); a1 = fmaf(w2c.w, hd2[7], a1);
      v = fmaf(sigm(a0+a1), AD2, BD2);
      f = swx<8>(v);  g = swx<16>(v);  o = swx<24>(v);
      dc2 = fmaf(f, dc2, v*g);                      // valid lanes 0..7
      float h2 = o * tanh_f(dc2);
      #pragma unroll
      for (int k=0;k<8;++k) hd2[k] = rl(h2, k);

      // ---- d3: din=8, h=16 (gate-per-lane, 64 gates)
      a0 = bd3; a1 = 0.f; float a2 = 0.f, a3 = 0.f;
      #pragma unroll
      for (int grp=0; grp<2; ++grp){
        float4 wq = d3v[grp*64+lane];
        a0 = fmaf(wq.x, hd2[grp*4  ], a0);
        a1 = fmaf(wq.y, hd2[grp*4+1], a1);
        a2 = fmaf(wq.z, hd2[grp*4+2], a2);
        a3 = fmaf(wq.w, hd2[grp*4+3], a3);
      }
      #pragma unroll
      for (int grp=0; grp<4; ++grp){
        float4 wq = d3v[(2+grp)*64+lane];
        a0 = fmaf(wq.x, hd3[grp*4  ], a0);
        a1 = fmaf(wq.y, hd3[grp*4+1], a1);
        a2 = fmaf(wq.z, hd3[grp*4+2], a2);
        a3 = fmaf(wq.w, hd3[grp*4+3], a3);
      }
      v = fmaf(sigm((a0+a1)+(a2+a3)), A1, B1);
      f = swx<16>(v);
      g = __shfl_xor(v, 32, 64);
      o = __shfl_xor(f, 32, 64);
      dc3 = fmaf(f, dc3, v*g);                      // valid lanes 0..15
      float h3 = o * tanh_f(dc3);
      #pragma unroll
      for (int k=0;k<16;++k) hd3[k] = rl(h3, k);

      // ---- final linear 16->32, coalesced store
      float4 woa = *(const float4*)(rw);
      float4 wob = *(const float4*)(rw+4);
      float4 woc = *(const float4*)(rw+8);
      float4 wod = *(const float4*)(rw+12);
      float ov0 = bo, ov1 = 0.f;
      ov0 = fmaf(woa.x, hd3[0], ov0);  ov1 = fmaf(woa.y, hd3[1], ov1);
      ov0 = fmaf(woa.z, hd3[2], ov0);  ov1 = fmaf(woa.w, hd3[3], ov1);
      ov0 = fmaf(wob.x, hd3[4], ov0);  ov1 = fmaf(wob.y, hd3[5], ov1);
      ov0 = fmaf(wob.z, hd3[6], ov0);  ov1 = fmaf(wob.w, hd3[7], ov1);
      ov0 = fmaf(woc.x, hd3[8], ov0);  ov1 = fmaf(woc.y, hd3[9], ov1);
      ov0 = fmaf(woc.z, hd3[10], ov0); ov1 = fmaf(woc.w, hd3[11], ov1);
      ov0 = fmaf(wod.x, hd3[12], ov0); ov1 = fmaf(wod.y, hd3[13], ov1);
      ov0 = fmaf(wod.z, hd3[14], ov0); ov1 = fmaf(wod.w, hd3[15], ov1);
      if (lane < 32) ob[t*32 + lane] = ov0 + ov1;
    }
  }
}

extern "C" void kernel_launch(void* const* d_in, const int* in_sizes, int n_in,
                              void* d_out, int out_size, void* d_ws, size_t ws_size,
                              hipStream_t stream) {
  (void)in_sizes; (void)n_in; (void)d_ws; (void)ws_size; (void)out_size;
  const float* x    = (const float*)d_in[0];
  const float* e1Wi = (const float*)d_in[1];
  const float* e1Wh = (const float*)d_in[2];
  const float* e1bi = (const float*)d_in[3];
  const float* e1bh = (const float*)d_in[4];
  const float* e2Wi = (const float*)d_in[5];
  const float* e2Wh = (const float*)d_in[6];
  const float* e2bi = (const float*)d_in[7];
  const float* e2bh = (const float*)d_in[8];
  const float* e3Wi = (const float*)d_in[9];
  const float* e3Wh = (const float*)d_in[10];
  const float* e3bi = (const float*)d_in[11];
  const float* e3bh = (const float*)d_in[12];
  const float* d1Wi = (const float*)d_in[13];
  const float* d1Wh = (const float*)d_in[14];
  const float* d1bi = (const float*)d_in[15];
  const float* d1bh = (const float*)d_in[16];
  const float* d2Wi = (const float*)d_in[17];
  const float* d2Wh = (const float*)d_in[18];
  const float* d2bi = (const float*)d_in[19];
  const float* d2bh = (const float*)d_in[20];
  const float* d3Wi = (const float*)d_in[21];
  const float* d3Wh = (const float*)d_in[22];
  const float* d3bi = (const float*)d_in[23];
  const float* d3bh = (const float*)d_in[24];
  const float* Wout = (const float*)d_in[25];
  const float* boutp= (const float*)d_in[26];
  float* out = (float*)d_out;

  lstm_ae_fused<<<1024, 256, 0, stream>>>(x,
      e1Wi, e1Wh, e1bi, e1bh,
      e2Wi, e2Wh, e2bi, e2bh,
      e3Wi, e3Wh, e3bi, e3bh,
      d1Wi, d1Wh, d1bi, d1bh,
      d2Wi, d2Wh, d2bi, d2bh,
      d3Wi, d3Wh, d3bi, d3bh,
      Wout, boutp, out);
}

// Round 6
// 265.977 us; speedup vs baseline: 1.2039x; 1.0640x over previous
//
#include <hip/hip_runtime.h>

#define LOG2E 1.44269504088896340736f

__device__ __forceinline__ float vexp2(float x){ float r; asm("v_exp_f32 %0, %1" : "=v"(r) : "v"(x)); return r; }
__device__ __forceinline__ float vrcp (float x){ float r; asm("v_rcp_f32 %0, %1" : "=v"(r) : "v"(x)); return r; }
template<int XM> __device__ __forceinline__ float swx(float v){
  return __int_as_float(__builtin_amdgcn_ds_swizzle(__float_as_int(v), (XM<<10)|0x1F));
}
__device__ __forceinline__ float sigm(float x){ return vrcp(1.0f + vexp2(x * (-LOG2E))); }
__device__ __forceinline__ float tanh_f(float x){
  float s = vrcp(1.0f + vexp2(x * (-2.0f*LOG2E)));
  return s + s - 1.0f;
}

// 2 batch elements per wave. Narrow layers (<=32 gates/batch) pack both
// batches in one 64-lane instruction stream (halves per-batch FMA + trans).
// Wide layers (e1,d3: 64 gates) run A,B sequentially but share one tanh(c)
// via lane-packing (cA lanes 0-15, cB lanes 16-31). Hidden state lives in
// LDS (ds_write + wave-uniform/per-half ds_read_b128) -> no readlane VALU.
__global__ void __launch_bounds__(256)
lstm_ae_fused(const float* __restrict__ x,
              const float* __restrict__ e1Wi, const float* __restrict__ e1Wh, const float* __restrict__ e1bi, const float* __restrict__ e1bh,
              const float* __restrict__ e2Wi, const float* __restrict__ e2Wh, const float* __restrict__ e2bi, const float* __restrict__ e2bh,
              const float* __restrict__ e3Wi, const float* __restrict__ e3Wh, const float* __restrict__ e3bi, const float* __restrict__ e3bh,
              const float* __restrict__ d1Wi, const float* __restrict__ d1Wh, const float* __restrict__ d1bi, const float* __restrict__ d1bh,
              const float* __restrict__ d2Wi, const float* __restrict__ d2Wh, const float* __restrict__ d2bi, const float* __restrict__ d2bh,
              const float* __restrict__ d3Wi, const float* __restrict__ d3Wh, const float* __restrict__ d3bi, const float* __restrict__ d3bh,
              const float* __restrict__ Wout, const float* __restrict__ bout,
              float* __restrict__ out)
{
  const int tid  = threadIdx.x;
  const int lane = tid & 63;
  const int wv   = tid >> 6;                 // wave 0..3
  const int gw   = blockIdx.x*4 + wv;        // global wave
  const int bA   = gw*2, bB = gw*2 + 1;
  const float* __restrict__ xbA = x + (size_t)bA * 4096;
  const float* __restrict__ xbB = x + (size_t)bB * 4096;
  float* __restrict__ obA = out + (size_t)bA * 4096;
  float* __restrict__ obB = out + (size_t)bB * 4096;

  // ---------------- LDS ----------------
  __shared__ float s_e1[13*64*4];   // per-lane quads: 0-7 w1i, 8-11 w1h, 12.x eb1
  __shared__ float s_e2[16*20];
  __shared__ float s_eb2[16];
  __shared__ float s_e3[4*8];
  __shared__ float s_d1[16*8];
  __shared__ float s_d2[32*20];
  __shared__ float s_d3[7*64*4];    // 0-1 wd3i, 2-5 wd3h, 6.x bd3
  __shared__ float s_wo[32*20];
  __shared__ float s_x [4][1024];   // per wave: [0..511] batch A chunk, [512..1023] B
  __shared__ float s_h1[4][64];     // A slots 0-15, B 16-31
  __shared__ float s_h2[4][64];     // A 0-3,  B 16-19
  __shared__ float s_h3[4][64];     // A 0,    B 16
  __shared__ float s_g1[4][64];     // decoder hd1: A 0-3, B 16-19
  __shared__ float s_g2[4][64];     // decoder hd2: A 0-7, B 32-39
  __shared__ float s_g3[4][64];     // decoder hd3: A 0-15, B 16-31

  // ---------------- one-time weight staging (g-gate rows pre-scaled x2) ----------------
  if (tid < 64){
    const int l = tid;
    const float A1l = (l>=32 && l<48) ? 2.f : 1.f;
    for (int k=0;k<32;++k) s_e1[((k>>2)*64+l)*4+(k&3)]      = e1Wi[l*32+k]*A1l;
    for (int k=0;k<16;++k) s_e1[(((k>>2)+8)*64+l)*4+(k&3)]  = e1Wh[l*16+k]*A1l;
    s_e1[(12*64+l)*4] = (e1bi[l]+e1bh[l])*A1l;
    for (int k=0;k<8;++k)  s_d3[((k>>2)*64+l)*4+(k&3)]      = d3Wi[l*8+k]*A1l;
    for (int k=0;k<16;++k) s_d3[(((k>>2)+2)*64+l)*4+(k&3)]  = d3Wh[l*16+k]*A1l;
    s_d3[(6*64+l)*4] = (d3bi[l]+d3bh[l])*A1l;
    if (l < 16){
      const float A2l = (l>=8 && l<12) ? 2.f : 1.f;
      for (int k=0;k<16;++k) s_e2[l*20+k]    = e2Wi[l*16+k]*A2l;
      for (int k=0;k<4;++k)  s_e2[l*20+16+k] = e2Wh[l*4+k]*A2l;
      s_eb2[l] = (e2bi[l]+e2bh[l])*A2l;
      for (int k=0;k<4;++k)  s_d1[l*8+k] = d1Wh[l*4+k]*A2l;
      s_d1[l*8+4] = d1Wi[l]*A2l;
      s_d1[l*8+5] = (d1bi[l]+d1bh[l])*A2l;
    }
    if (l < 4){
      const float A3l = (l==2) ? 2.f : 1.f;
      for (int k=0;k<4;++k) s_e3[l*8+k] = e3Wi[l*4+k]*A3l;
      s_e3[l*8+4] = e3Wh[l]*A3l;
      s_e3[l*8+5] = (e3bi[l]+e3bh[l])*A3l;
    }
    if (l < 32){
      const float AD2l = (l>=16 && l<24) ? 2.f : 1.f;
      for (int k=0;k<4;++k) s_d2[l*20+k]   = d2Wi[l*4+k]*AD2l;
      for (int k=0;k<8;++k) s_d2[l*20+4+k] = d2Wh[l*8+k]*AD2l;
      s_d2[l*20+12] = (d2bi[l]+d2bh[l])*AD2l;
      for (int k=0;k<16;++k) s_wo[l*20+k] = Wout[l*16+k];
      s_wo[l*20+16] = bout[l];
    }
  }
  __syncthreads();

  // gate-role affine (A scale folded into weights; B offset applied after sigm)
  const bool isg1 = (lane >= 32) && (lane < 48);
  const bool isg2 = ((lane & 15) >= 8) && ((lane & 15) < 12);
  const bool isg3 = ((lane & 3) == 2);
  const bool isgD2= ((lane & 31) >= 16) && ((lane & 31) < 24);
  const float A1 = isg1 ? 2.f : 1.f,  B1 = isg1 ? -1.f : 0.f;
  const float A2 = isg2 ? 2.f : 1.f,  B2 = isg2 ? -1.f : 0.f;
  const float A3 = isg3 ? 2.f : 1.f,  B3 = isg3 ? -1.f : 0.f;
  const float AD2= isgD2? 2.f : 1.f,  BD2= isgD2? -1.f : 0.f;
  const bool selA = ((lane & 16) == 0);      // pack select for e1/d3
  const int  h16  = lane & 16;               // 0/16  : half base (16-packing)
  const int  h32  = lane & 32;               // 0/32  : half base (32-packing)
  const int  h32s = (lane & 32) >> 1;        // 0/16

  const float4* e1v = (const float4*)s_e1;
  const float4* d3v = (const float4*)s_d3;
  const float* r2  = &s_e2[(lane&15)*20];
  const float* r3  = &s_e3[(lane&3)*8];
  const float* rd1 = &s_d1[(lane&15)*8];
  const float* rd2 = &s_d2[(lane&31)*20];
  const float* rw  = &s_wo[(lane&31)*20];

  // ======================= ENCODER =======================
  {
    const float eb1 = s_e1[(12*64+lane)*4];
    const float eb2 = s_eb2[lane&15];
    const float w3h = r3[4], eb3 = r3[5];

    s_h1[wv][lane] = 0.f;  s_h2[wv][lane] = 0.f;  s_h3[wv][lane] = 0.f;
    float c1 = 0.f, c2 = 0.f, c3 = 0.f;

    for (int tc=0; tc<128; tc+=16){
      // stage 16 steps of x for both batches (wave-internal, no barrier)
      {
        const float4* xgA = (const float4*)(xbA + tc*32);
        const float4* xgB = (const float4*)(xbB + tc*32);
        float4* sxA = (float4*)&s_x[wv][0];
        float4* sxB = (float4*)&s_x[wv][512];
        sxA[lane]    = xgA[lane];
        sxA[64+lane] = xgA[64+lane];
        sxB[lane]    = xgB[lane];
        sxB[64+lane] = xgB[64+lane];
      }
      for (int tt=0; tt<16; ++tt){
        const float4* xA4 = (const float4*)&s_x[wv][tt*32];
        const float4* xB4 = (const float4*)&s_x[wv][512+tt*32];
        const float4* h1A = (const float4*)&s_h1[wv][0];
        const float4* h1B = (const float4*)&s_h1[wv][16];

        // ---- e1: din=32, h=16; batches sequential, shared weights ----
        float aA0=eb1, aA1=0.f, aA2=0.f, aA3=0.f;
        float aB0=eb1, aB1=0.f, aB2=0.f, aB3=0.f;
        #pragma unroll
        for (int grp=0; grp<8; ++grp){
          float4 wq = e1v[grp*64+lane];
          float4 xa = xA4[grp], xb = xB4[grp];
          aA0 = fmaf(wq.x, xa.x, aA0);  aB0 = fmaf(wq.x, xb.x, aB0);
          aA1 = fmaf(wq.y, xa.y, aA1);  aB1 = fmaf(wq.y, xb.y, aB1);
          aA2 = fmaf(wq.z, xa.z, aA2);  aB2 = fmaf(wq.z, xb.z, aB2);
          aA3 = fmaf(wq.w, xa.w, aA3);  aB3 = fmaf(wq.w, xb.w, aB3);
        }
        #pragma unroll
        for (int grp=0; grp<4; ++grp){
          float4 wq = e1v[(8+grp)*64+lane];
          float4 ha = h1A[grp], hb = h1B[grp];
          aA0 = fmaf(wq.x, ha.x, aA0);  aB0 = fmaf(wq.x, hb.x, aB0);
          aA1 = fmaf(wq.y, ha.y, aA1);  aB1 = fmaf(wq.y, hb.y, aB1);
          aA2 = fmaf(wq.z, ha.z, aA2);  aB2 = fmaf(wq.z, hb.z, aB2);
          aA3 = fmaf(wq.w, ha.w, aA3);  aB3 = fmaf(wq.w, hb.w, aB3);
        }
        float vA = fmaf(sigm((aA0+aA1)+(aA2+aA3)), A1, B1);
        float vB = fmaf(sigm((aB0+aB1)+(aB2+aB3)), A1, B1);
        float t1A = swx<16>(vA);
        float t2A = __shfl_xor(vA, 32, 64);
        float t3A = swx<16>(t2A);
        float t1B = swx<16>(vB);
        float t2B = __shfl_xor(vB, 32, 64);
        float t3B = swx<16>(t2B);
        float ip = selA ? vA  : t1B;   // i gates: A lanes0-15, B lanes16-31
        float fp = selA ? t1A : vB;
        float gp = selA ? t2A : t3B;
        float op = selA ? t3A : t2B;
        c1 = fmaf(fp, c1, ip*gp);
        float h1v = op * tanh_f(c1);                 // one tanh for both batches
        s_h1[wv][lane] = h1v;

        // ---- e2: din=16, h=4; both batches packed (A lanes 0-15, B 16-31) ----
        float4 w20 = *(const float4*)(r2);
        float4 w21 = *(const float4*)(r2+4);
        float4 w22 = *(const float4*)(r2+8);
        float4 w23 = *(const float4*)(r2+12);
        float4 w24 = *(const float4*)(r2+16);
        const float4* h1s = (const float4*)&s_h1[wv][h16];
        float4 q0 = h1s[0], q1 = h1s[1], q2 = h1s[2], q3 = h1s[3];
        float4 h2q = *(const float4*)&s_h2[wv][h16];
        float a0 = eb2, a1 = 0.f;
        a0 = fmaf(w20.x,q0.x,a0);  a1 = fmaf(w20.y,q0.y,a1);
        a0 = fmaf(w20.z,q0.z,a0);  a1 = fmaf(w20.w,q0.w,a1);
        a0 = fmaf(w21.x,q1.x,a0);  a1 = fmaf(w21.y,q1.y,a1);
        a0 = fmaf(w21.z,q1.z,a0);  a1 = fmaf(w21.w,q1.w,a1);
        a0 = fmaf(w22.x,q2.x,a0);  a1 = fmaf(w22.y,q2.y,a1);
        a0 = fmaf(w22.z,q2.z,a0);  a1 = fmaf(w22.w,q2.w,a1);
        a0 = fmaf(w23.x,q3.x,a0);  a1 = fmaf(w23.y,q3.y,a1);
        a0 = fmaf(w23.z,q3.z,a0);  a1 = fmaf(w23.w,q3.w,a1);
        a0 = fmaf(w24.x,h2q.x,a0); a1 = fmaf(w24.y,h2q.y,a1);
        a0 = fmaf(w24.z,h2q.z,a0); a1 = fmaf(w24.w,h2q.w,a1);
        float v2 = fmaf(sigm(a0+a1), A2, B2);
        float f2 = swx<4>(v2), g2 = swx<8>(v2), o2 = swx<12>(v2);
        c2 = fmaf(f2, c2, v2*g2);                    // valid lanes 0-3, 16-19
        float h2v = o2 * tanh_f(c2);
        s_h2[wv][lane] = h2v;

        // ---- e3: din=4, h=1; packed (A lanes 0-3, B 16-19) ----
        float4 w30 = *(const float4*)(r3);
        float4 h2s = *(const float4*)&s_h2[wv][h16];
        float h3p  = s_h3[wv][h16];
        float a = fmaf(w3h, h3p, eb3);
        a = fmaf(w30.x, h2s.x, a);
        a = fmaf(w30.y, h2s.y, a);
        a = fmaf(w30.z, h2s.z, a);
        a = fmaf(w30.w, h2s.w, a);
        float v3 = fmaf(sigm(a), A3, B3);
        float f3 = swx<1>(v3), g3 = swx<2>(v3), o3 = swx<3>(v3);
        c3 = fmaf(f3, c3, v3*g3);                    // valid lanes 0, 16
        float h3v = o3 * tanh_f(c3);
        s_h3[wv][lane] = h3v;
      }
    }
  }

  // ======================= DECODER =======================
  {
    const float encv = s_h3[wv][h16];
    const float p1  = fmaf(rd1[4], encv, rd1[5]);    // d1 input term, const over t
    const float bd2 = rd2[12];
    const float bd3 = s_d3[(6*64+lane)*4];
    const float bo  = rw[16];

    s_g1[wv][lane] = 0.f;  s_g2[wv][lane] = 0.f;  s_g3[wv][lane] = 0.f;
    float dc1 = 0.f, dc2 = 0.f, dc3 = 0.f;
    float* __restrict__ obSel = (lane < 32) ? (obA + lane) : (obB + lane - 32);

    for (int t=0; t<128; ++t){
      // ---- d1: din=1 (const input), h=4; packed (A 0-15, B 16-31) ----
      float4 wd1 = *(const float4*)(rd1);
      float4 g1q = *(const float4*)&s_g1[wv][h16];
      float a0 = p1, a1 = 0.f;
      a0 = fmaf(wd1.x, g1q.x, a0); a1 = fmaf(wd1.y, g1q.y, a1);
      a0 = fmaf(wd1.z, g1q.z, a0); a1 = fmaf(wd1.w, g1q.w, a1);
      float v1 = fmaf(sigm(a0+a1), A2, B2);
      float f1 = swx<4>(v1), gg1 = swx<8>(v1), o1 = swx<12>(v1);
      dc1 = fmaf(f1, dc1, v1*gg1);                  // valid 0-3, 16-19
      float h1v = o1 * tanh_f(dc1);
      s_g1[wv][lane] = h1v;

      // ---- d2: din=4, h=8; packed (A lanes 0-31, B 32-63) ----
      float4 w2a = *(const float4*)(rd2);
      float4 w2b = *(const float4*)(rd2+4);
      float4 w2c = *(const float4*)(rd2+8);
      float4 g1s = *(const float4*)&s_g1[wv][h32s];
      float4 g2a = *(const float4*)&s_g2[wv][h32];
      float4 g2b = *(const float4*)&s_g2[wv][h32+4];
      a0 = bd2; a1 = 0.f;
      a0 = fmaf(w2a.x, g1s.x, a0); a1 = fmaf(w2a.y, g1s.y, a1);
      a0 = fmaf(w2a.z, g1s.z, a0); a1 = fmaf(w2a.w, g1s.w, a1);
      a0 = fmaf(w2b.x, g2a.x, a0); a1 = fmaf(w2b.y, g2a.y, a1);
      a0 = fmaf(w2b.z, g2a.z, a0); a1 = fmaf(w2b.w, g2a.w, a1);
      a0 = fmaf(w2c.x, g2b.x, a0); a1 = fmaf(w2c.y, g2b.y, a1);
      a0 = fmaf(w2c.z, g2b.z, a0); a1 = fmaf(w2c.w, g2b.w, a1);
      float v2 = fmaf(sigm(a0+a1), AD2, BD2);
      float f2 = swx<8>(v2), gg2 = swx<16>(v2), o2 = swx<24>(v2);
      dc2 = fmaf(f2, dc2, v2*gg2);                  // valid 0-7, 32-39
      float h2v = o2 * tanh_f(dc2);
      s_g2[wv][lane] = h2v;

      // ---- d3: din=8, h=16; batches sequential, shared weights ----
      const float4* g2A = (const float4*)&s_g2[wv][0];
      const float4* g2B = (const float4*)&s_g2[wv][32];
      const float4* g3A = (const float4*)&s_g3[wv][0];
      const float4* g3B = (const float4*)&s_g3[wv][16];
      float aA0=bd3, aA1=0.f, aA2=0.f, aA3=0.f;
      float aB0=bd3, aB1=0.f, aB2=0.f, aB3=0.f;
      #pragma unroll
      for (int grp=0; grp<2; ++grp){
        float4 wq = d3v[grp*64+lane];
        float4 ha = g2A[grp], hb = g2B[grp];
        aA0 = fmaf(wq.x, ha.x, aA0);  aB0 = fmaf(wq.x, hb.x, aB0);
        aA1 = fmaf(wq.y, ha.y, aA1);  aB1 = fmaf(wq.y, hb.y, aB1);
        aA2 = fmaf(wq.z, ha.z, aA2);  aB2 = fmaf(wq.z, hb.z, aB2);
        aA3 = fmaf(wq.w, ha.w, aA3);  aB3 = fmaf(wq.w, hb.w, aB3);
      }
      #pragma unroll
      for (int grp=0; grp<4; ++grp){
        float4 wq = d3v[(2+grp)*64+lane];
        float4 ha = g3A[grp], hb = g3B[grp];
        aA0 = fmaf(wq.x, ha.x, aA0);  aB0 = fmaf(wq.x, hb.x, aB0);
        aA1 = fmaf(wq.y, ha.y, aA1);  aB1 = fmaf(wq.y, hb.y, aB1);
        aA2 = fmaf(wq.z, ha.z, aA2);  aB2 = fmaf(wq.z, hb.z, aB2);
        aA3 = fmaf(wq.w, ha.w, aA3);  aB3 = fmaf(wq.w, hb.w, aB3);
      }
      float vA = fmaf(sigm((aA0+aA1)+(aA2+aA3)), A1, B1);
      float vB = fmaf(sigm((aB0+aB1)+(aB2+aB3)), A1, B1);
      float t1A = swx<16>(vA);
      float t2A = __shfl_xor(vA, 32, 64);
      float t3A = swx<16>(t2A);
      float t1B = swx<16>(vB);
      float t2B = __shfl_xor(vB, 32, 64);
      float t3B = swx<16>(t2B);
      float ip = selA ? vA  : t1B;
      float fp = selA ? t1A : vB;
      float gp = selA ? t2A : t3B;
      float op = selA ? t3A : t2B;
      dc3 = fmaf(fp, dc3, ip*gp);
      float h3v = op * tanh_f(dc3);
      s_g3[wv][lane] = h3v;                          // A 0-15, B 16-31

      // ---- final linear 16->32; A outputs lanes 0-31, B lanes 32-63 ----
      float4 woa = *(const float4*)(rw);
      float4 wob = *(const float4*)(rw+4);
      float4 woc = *(const float4*)(rw+8);
      float4 wod = *(const float4*)(rw+12);
      const float4* g3s = (const float4*)&s_g3[wv][h32s];
      float4 u0 = g3s[0], u1 = g3s[1], u2 = g3s[2], u3 = g3s[3];
      float ov0 = bo, ov1 = 0.f;
      ov0 = fmaf(woa.x, u0.x, ov0);  ov1 = fmaf(woa.y, u0.y, ov1);
      ov0 = fmaf(woa.z, u0.z, ov0);  ov1 = fmaf(woa.w, u0.w, ov1);
      ov0 = fmaf(wob.x, u1.x, ov0);  ov1 = fmaf(wob.y, u1.y, ov1);
      ov0 = fmaf(wob.z, u1.z, ov0);  ov1 = fmaf(wob.w, u1.w, ov1);
      ov0 = fmaf(woc.x, u2.x, ov0);  ov1 = fmaf(woc.y, u2.y, ov1);
      ov0 = fmaf(woc.z, u2.z, ov0);  ov1 = fmaf(woc.w, u2.w, ov1);
      ov0 = fmaf(wod.x, u3.x, ov0);  ov1 = fmaf(wod.y, u3.y, ov1);
      ov0 = fmaf(wod.z, u3.z, ov0);  ov1 = fmaf(wod.w, u3.w, ov1);
      obSel[t*32] = ov0 + ov1;
    }
  }
}

extern "C" void kernel_launch(void* const* d_in, const int* in_sizes, int n_in,
                              void* d_out, int out_size, void* d_ws, size_t ws_size,
                              hipStream_t stream) {
  (void)in_sizes; (void)n_in; (void)d_ws; (void)ws_size; (void)out_size;
  const float* x    = (const float*)d_in[0];
  const float* e1Wi = (const float*)d_in[1];
  const float* e1Wh = (const float*)d_in[2];
  const float* e1bi = (const float*)d_in[3];
  const float* e1bh = (const float*)d_in[4];
  const float* e2Wi = (const float*)d_in[5];
  const float* e2Wh = (const float*)d_in[6];
  const float* e2bi = (const float*)d_in[7];
  const float* e2bh = (const float*)d_in[8];
  const float* e3Wi = (const float*)d_in[9];
  const float* e3Wh = (const float*)d_in[10];
  const float* e3bi = (const float*)d_in[11];
  const float* e3bh = (const float*)d_in[12];
  const float* d1Wi = (const float*)d_in[13];
  const float* d1Wh = (const float*)d_in[14];
  const float* d1bi = (const float*)d_in[15];
  const float* d1bh = (const float*)d_in[16];
  const float* d2Wi = (const float*)d_in[17];
  const float* d2Wh = (const float*)d_in[18];
  const float* d2bi = (const float*)d_in[19];
  const float* d2bh = (const float*)d_in[20];
  const float* d3Wi = (const float*)d_in[21];
  const float* d3Wh = (const float*)d_in[22];
  const float* d3bi = (const float*)d_in[23];
  const float* d3bh = (const float*)d_in[24];
  const float* Wout = (const float*)d_in[25];
  const float* boutp= (const float*)d_in[26];
  float* out = (float*)d_out;

  lstm_ae_fused<<<512, 256, 0, stream>>>(x,
      e1Wi, e1Wh, e1bi, e1bh,
      e2Wi, e2Wh, e2bi, e2bh,
      e3Wi, e3Wh, e3bi, e3bh,
      d1Wi, d1Wh, d1bi, d1bh,
      d2Wi, d2Wh, d2bi, d2bh,
      d3Wi, d3Wh, d3bi, d3bh,
      Wout, boutp, out);
}